// Round 1
// baseline (933.317 us; speedup 1.0000x reference)
//
#include <hip/hip_runtime.h>
#include <hip/hip_bf16.h>
#include <math.h>

#define HID 256

__device__ __forceinline__ float gelu_tanh(float x){
    float x3 = x*x*x;
    float t = tanhf(0.7978845608028654f*(x + 0.044715f*x3));
    return 0.5f*x*(1.0f+t);
}

__device__ __forceinline__ float wave_sum(float v){
    #pragma unroll
    for(int o=32;o>0;o>>=1) v += __shfl_xor(v, o, 64);
    return v;
}

__global__ void k_zero_cnt(int* cnt, int N){
    int i = blockIdx.x*blockDim.x + threadIdx.x;
    if(i<N) cnt[i]=0;
}

__global__ void k_count(const int* __restrict__ dst, int* __restrict__ cnt, int E){
    int e = blockIdx.x*blockDim.x + threadIdx.x;
    if(e<E) atomicAdd(&cnt[dst[e]], 1);
}

// single-block exclusive scan of cnt -> indptr/cursor, plus dinv = rsqrt(cnt+1)
__global__ __launch_bounds__(1024) void k_scan(const int* __restrict__ cnt, int* __restrict__ indptr,
    int* __restrict__ cursor, float* __restrict__ dinv, int N){
    __shared__ int part[1024];
    int t = threadIdx.x;
    int CH = (N+1023)>>10;
    int base = t*CH;
    int s=0;
    for(int i=0;i<CH;i++){ int idx=base+i; if(idx<N) s+=cnt[idx]; }
    part[t]=s; __syncthreads();
    for(int off=1; off<1024; off<<=1){
        int v = part[t];
        int add = (t>=off)? part[t-off]:0;
        __syncthreads();
        part[t] = v+add;
        __syncthreads();
    }
    int run = part[t]-s;  // exclusive prefix of this thread's chunk
    for(int i=0;i<CH;i++){
        int idx=base+i;
        if(idx<N){
            int c = cnt[idx];
            indptr[idx]=run; cursor[idx]=run;
            dinv[idx] = rsqrtf((float)(c+1));
            run += c;
        }
    }
    if(t==1023) indptr[N]=run;
}

__global__ void k_fill(const int* __restrict__ src, const int* __restrict__ dst,
    int* __restrict__ cursor, int* __restrict__ csr, int E){
    int e = blockIdx.x*blockDim.x + threadIdx.x;
    if(e<E){
        int pos = atomicAdd(&cursor[dst[e]], 1);
        csr[pos] = src[e];
    }
}

// Z[n][j] = (sum_k X[n][k]*W[k][j]) * (dinv ? dinv[n] : 1)
template<int K>
__global__ __launch_bounds__(256) void k_gemm(const float* __restrict__ X,
    const float* __restrict__ W, const float* __restrict__ dinv,
    float* __restrict__ Z, int N)
{
    __shared__ float xs[32][64];
    const int j = threadIdx.x;
    const int row0 = blockIdx.x*32;
    float acc[32];
    #pragma unroll
    for(int r=0;r<32;r++) acc[r]=0.0f;
    for(int kt=0; kt<K; kt+=64){
        #pragma unroll
        for(int i=0;i<2;i++){
            int idx = threadIdx.x + i*256;
            int r = idx>>4;
            int c = (idx&15)<<2;
            int row = row0 + r; if(row>=N) row=N-1;
            float4 v = *reinterpret_cast<const float4*>(&X[(size_t)row*K + kt + c]);
            *reinterpret_cast<float4*>(&xs[r][c]) = v;
        }
        __syncthreads();
        for(int k=0;k<64;k+=4){
            float w0 = W[(size_t)(kt+k  )*HID + j];
            float w1 = W[(size_t)(kt+k+1)*HID + j];
            float w2 = W[(size_t)(kt+k+2)*HID + j];
            float w3 = W[(size_t)(kt+k+3)*HID + j];
            #pragma unroll
            for(int r=0;r<32;r++){
                float4 xv = *reinterpret_cast<const float4*>(&xs[r][k]);
                acc[r] = fmaf(xv.x, w0, acc[r]);
                acc[r] = fmaf(xv.y, w1, acc[r]);
                acc[r] = fmaf(xv.z, w2, acc[r]);
                acc[r] = fmaf(xv.w, w3, acc[r]);
            }
        }
        __syncthreads();
    }
    #pragma unroll
    for(int r=0;r<32;r++){
        int row = row0+r;
        if(row<N){
            float v = acc[r];
            if(dinv) v *= dinv[row];
            Z[(size_t)row*HID + j] = v;
        }
    }
}

// input block epilogue: h0 = xcur = LN(gelu(Z + b))
__global__ __launch_bounds__(256) void k_ln_in(const float* __restrict__ Z, const float* __restrict__ b,
    const float* __restrict__ g, const float* __restrict__ be,
    float* __restrict__ h0, float* __restrict__ xcur, int N)
{
    int wave = threadIdx.x>>6, lane = threadIdx.x&63;
    int n = blockIdx.x*4 + wave;
    if(n>=N) return;
    const float4* Z4 = reinterpret_cast<const float4*>(Z);
    float4 v = Z4[(size_t)n*64 + lane];
    float4 bb = reinterpret_cast<const float4*>(b)[lane];
    v.x = gelu_tanh(v.x+bb.x);
    v.y = gelu_tanh(v.y+bb.y);
    v.z = gelu_tanh(v.z+bb.z);
    v.w = gelu_tanh(v.w+bb.w);
    float s1 = wave_sum(v.x+v.y+v.z+v.w);
    float mu = s1*(1.0f/256.0f);
    float dx=v.x-mu, dy=v.y-mu, dz=v.z-mu, dw=v.w-mu;
    float s2 = wave_sum(dx*dx+dy*dy+dz*dz+dw*dw);
    float rs = rsqrtf(s2*(1.0f/256.0f)+1e-5f);
    float4 gg = reinterpret_cast<const float4*>(g)[lane];
    float4 b2 = reinterpret_cast<const float4*>(be)[lane];
    float4 o;
    o.x = dx*rs*gg.x + b2.x;
    o.y = dy*rs*gg.y + b2.y;
    o.z = dz*rs*gg.z + b2.z;
    o.w = dw*rs*gg.w + b2.w;
    reinterpret_cast<float4*>(h0  )[(size_t)n*64+lane]=o;
    reinterpret_cast<float4*>(xcur)[(size_t)n*64+lane]=o;
}

// fused: acc = z[n] + sum_{e in CSR[n]} z[src_e]; v = dinv[n]*acc + bc;
// out = LN(gelu(v)); xcur += 0.9*out + 0.1*h0
__global__ __launch_bounds__(256) void k_agg_ln(const float* __restrict__ Z,
    const int* __restrict__ indptr, const int* __restrict__ csr,
    const float* __restrict__ dinv, const float* __restrict__ bc,
    const float* __restrict__ gc, const float* __restrict__ bec,
    const float* __restrict__ h0, float* __restrict__ xcur, int N)
{
    int wave = threadIdx.x>>6, lane = threadIdx.x&63;
    int n = blockIdx.x*4 + wave;
    if(n>=N) return;
    const float4* Z4 = reinterpret_cast<const float4*>(Z);
    float4 acc = Z4[(size_t)n*64+lane];   // self loop (z already dinv[src]-scaled)
    int e0 = indptr[n], e1 = indptr[n+1];
    for(int e=e0;e<e1;e++){
        int s = csr[e];
        float4 zv = Z4[(size_t)s*64+lane];
        acc.x+=zv.x; acc.y+=zv.y; acc.z+=zv.z; acc.w+=zv.w;
    }
    float dn = dinv[n];
    float4 bb = reinterpret_cast<const float4*>(bc)[lane];
    float4 v;
    v.x = gelu_tanh(fmaf(dn,acc.x,bb.x));
    v.y = gelu_tanh(fmaf(dn,acc.y,bb.y));
    v.z = gelu_tanh(fmaf(dn,acc.z,bb.z));
    v.w = gelu_tanh(fmaf(dn,acc.w,bb.w));
    float s1 = wave_sum(v.x+v.y+v.z+v.w);
    float mu = s1*(1.0f/256.0f);
    float dx=v.x-mu, dy=v.y-mu, dz=v.z-mu, dw=v.w-mu;
    float s2 = wave_sum(dx*dx+dy*dy+dz*dz+dw*dw);
    float rs = rsqrtf(s2*(1.0f/256.0f)+1e-5f);
    float4 gg = reinterpret_cast<const float4*>(gc)[lane];
    float4 b2 = reinterpret_cast<const float4*>(bec)[lane];
    float4 o;
    o.x = dx*rs*gg.x + b2.x;
    o.y = dy*rs*gg.y + b2.y;
    o.z = dz*rs*gg.z + b2.z;
    o.w = dw*rs*gg.w + b2.w;
    float4 h  = reinterpret_cast<const float4*>(h0)[(size_t)n*64+lane];
    float4 xc = reinterpret_cast<float4*>(xcur)[(size_t)n*64+lane];
    xc.x += 0.9f*o.x + 0.1f*h.x;
    xc.y += 0.9f*o.y + 0.1f*h.y;
    xc.z += 0.9f*o.z + 0.1f*h.z;
    xc.w += 0.9f*o.w + 0.1f*h.w;
    reinterpret_cast<float4*>(xcur)[(size_t)n*64+lane] = xc;
}

extern "C" void kernel_launch(void* const* d_in, const int* in_sizes, int n_in,
                              void* d_out, int out_size, void* d_ws, size_t ws_size,
                              hipStream_t stream){
    const float* x     = (const float*)d_in[0];
    const int*   ei    = (const int*)d_in[1];
    const float* W_in  = (const float*)d_in[2];
    const float* b_in  = (const float*)d_in[3];
    const float* g_in  = (const float*)d_in[4];
    const float* be_in = (const float*)d_in[5];
    const float* Wc    = (const float*)d_in[6];
    const float* bc    = (const float*)d_in[7];
    const float* gc    = (const float*)d_in[8];
    const float* bec   = (const float*)d_in[9];
    const int N = in_sizes[0]/128;
    const int E = in_sizes[1]/2;
    const int* src = ei;
    const int* dst = ei + E;
    float* xcur = (float*)d_out;

    char* w = (char*)d_ws;
    float* h0   = (float*)w; w += (size_t)N*HID*4;
    float* z    = (float*)w; w += (size_t)N*HID*4;
    float* dinv = (float*)w; w += (size_t)N*4;
    int* cnt    = (int*)w;   w += (size_t)N*4;
    int* cursor = (int*)w;   w += (size_t)N*4;
    int* csr    = (int*)w;   w += (size_t)E*4;
    int* indptr = (int*)w;   w += (size_t)(N+1)*4;

    k_zero_cnt<<<(N+255)/256,256,0,stream>>>(cnt,N);
    k_count<<<(E+255)/256,256,0,stream>>>(dst,cnt,E);
    k_scan<<<1,1024,0,stream>>>(cnt,indptr,cursor,dinv,N);
    k_fill<<<(E+255)/256,256,0,stream>>>(src,dst,cursor,csr,E);

    k_gemm<128><<<(N+31)/32,256,0,stream>>>(x, W_in, nullptr, z, N);
    k_ln_in<<<(N+3)/4,256,0,stream>>>(z, b_in, g_in, be_in, h0, xcur, N);
    for(int l=0;l<6;l++){
        k_gemm<256><<<(N+31)/32,256,0,stream>>>(xcur, Wc+(size_t)l*HID*HID, dinv, z, N);
        k_agg_ln<<<(N+3)/4,256,0,stream>>>(z, indptr, csr, dinv, bc+(size_t)l*HID,
                                           gc+(size_t)l*HID, bec+(size_t)l*HID, h0, xcur, N);
    }
}

// Round 2
// 504.858 us; speedup vs baseline: 1.8487x; 1.8487x over previous
//
#include <hip/hip_runtime.h>
#include <hip/hip_bf16.h>
#include <math.h>

#define HID 256
typedef __attribute__((ext_vector_type(8))) short s16x8;
typedef __attribute__((ext_vector_type(4))) float f32x4;

__device__ __forceinline__ ushort f2bf(float f){
    uint u = __float_as_uint(f);
    u += 0x7FFF + ((u>>16)&1);
    return (ushort)(u>>16);
}
__device__ __forceinline__ float bf2f(ushort b){
    return __uint_as_float(((uint)b)<<16);
}
__device__ __forceinline__ float4 bf4_to_f4(ushort4 u){
    return make_float4(bf2f(u.x), bf2f(u.y), bf2f(u.z), bf2f(u.w));
}

__device__ __forceinline__ float gelu_tanh(float x){
    float x3 = x*x*x;
    float t = tanhf(0.7978845608028654f*(x + 0.044715f*x3));
    return 0.5f*x*(1.0f+t);
}

__device__ __forceinline__ float wave_sum(float v){
    #pragma unroll
    for(int o=32;o>0;o>>=1) v += __shfl_xor(v, o, 64);
    return v;
}

__global__ void k_zero_cnt(int* cnt, int N){
    int i = blockIdx.x*blockDim.x + threadIdx.x;
    if(i<N) cnt[i]=0;
}

__global__ void k_count(const int* __restrict__ dst, int* __restrict__ cnt, int E){
    int e = blockIdx.x*blockDim.x + threadIdx.x;
    if(e<E) atomicAdd(&cnt[dst[e]], 1);
}

__global__ __launch_bounds__(1024) void k_scan(const int* __restrict__ cnt, int* __restrict__ indptr,
    int* __restrict__ cursor, float* __restrict__ dinv, int N){
    __shared__ int part[1024];
    int t = threadIdx.x;
    int CH = (N+1023)>>10;
    int base = t*CH;
    int s=0;
    for(int i=0;i<CH;i++){ int idx=base+i; if(idx<N) s+=cnt[idx]; }
    part[t]=s; __syncthreads();
    for(int off=1; off<1024; off<<=1){
        int v = part[t];
        int add = (t>=off)? part[t-off]:0;
        __syncthreads();
        part[t] = v+add;
        __syncthreads();
    }
    int run = part[t]-s;
    for(int i=0;i<CH;i++){
        int idx=base+i;
        if(idx<N){
            int c = cnt[idx];
            indptr[idx]=run; cursor[idx]=run;
            dinv[idx] = rsqrtf((float)(c+1));
            run += c;
        }
    }
    if(t==1023) indptr[N]=run;
}

__global__ void k_fill(const int* __restrict__ src, const int* __restrict__ dst,
    int* __restrict__ cursor, int* __restrict__ csr, int E){
    int e = blockIdx.x*blockDim.x + threadIdx.x;
    if(e<E){
        int pos = atomicAdd(&cursor[dst[e]], 1);
        csr[pos] = src[e];
    }
}

// fp32 -> bf16 flat convert, 4 elems/thread
__global__ void k_cvt(const float* __restrict__ in, ushort* __restrict__ out, int total4){
    int i = blockIdx.x*blockDim.x + threadIdx.x;
    if(i < total4){
        float4 v = reinterpret_cast<const float4*>(in)[i];
        ushort4 o; o.x=f2bf(v.x); o.y=f2bf(v.y); o.z=f2bf(v.z); o.w=f2bf(v.w);
        reinterpret_cast<ushort4*>(out)[i] = o;
    }
}

// W [K][256] fp32 -> fragment-shuffled bf16: Wb[((kb*256+n)*4+hi)*8+ii], k = kb*32+hi*8+ii
__global__ void k_cvt_win(const float* __restrict__ W, ushort* __restrict__ Wb){
    int i = blockIdx.x*blockDim.x + threadIdx.x;
    if(i >= 128*256) return;
    int k = i >> 8, n = i & 255;
    int kb = k>>5, hi=(k>>3)&3, ii=k&7;
    Wb[((kb*256+n)*4+hi)*8 + ii] = f2bf(W[i]);
}
__global__ void k_cvt_wc(const float* __restrict__ W, ushort* __restrict__ Wb){
    int i = blockIdx.x*blockDim.x + threadIdx.x;
    if(i >= 6*65536) return;
    int l = i >> 16;
    int k = (i>>8)&255, n = i&255;
    int kb = k>>5, hi=(k>>3)&3, ii=k&7;
    Wb[l*65536 + ((kb*256+n)*4+hi)*8 + ii] = f2bf(W[i]);
}

// Z[n][j] = bf16( (sum_k A[n][k]*W[k][j]) * (dinv?dinv[n]:1) )
// per block: 32 rows x 256 cols; wave wc owns 64 cols; no LDS, direct frag loads.
template<int K>
__global__ __launch_bounds__(256) void k_gemm_mfma(const ushort* __restrict__ A,
    const ushort* __restrict__ Wb, const float* __restrict__ dinv,
    ushort* __restrict__ Z, int N)
{
    const int lane = threadIdx.x & 63;
    const int wc = threadIdx.x >> 6;
    const int lr = lane & 15;
    const int hi = lane >> 4;
    const int row0 = blockIdx.x*32;
    f32x4 acc[2][4];
    #pragma unroll
    for(int m=0;m<2;m++)
        #pragma unroll
        for(int n=0;n<4;n++){ acc[m][n].x=0.f; acc[m][n].y=0.f; acc[m][n].z=0.f; acc[m][n].w=0.f; }

    int r0 = row0 + lr;      if(r0 >= N) r0 = N-1;
    int r1 = row0 + 16 + lr; if(r1 >= N) r1 = N-1;
    const ushort* ap0 = A + (size_t)r0*K + hi*8;
    const ushort* ap1 = A + (size_t)r1*K + hi*8;
    const ushort* bp  = Wb + (wc*64 + lr)*32 + hi*8;

    #pragma unroll
    for(int kb=0; kb<K/32; kb++){
        s16x8 a0 = *reinterpret_cast<const s16x8*>(ap0 + kb*32);
        s16x8 a1 = *reinterpret_cast<const s16x8*>(ap1 + kb*32);
        s16x8 b[4];
        #pragma unroll
        for(int nf=0;nf<4;nf++)
            b[nf] = *reinterpret_cast<const s16x8*>(bp + kb*8192 + nf*512);
        #pragma unroll
        for(int nf=0;nf<4;nf++){
            acc[0][nf] = __builtin_amdgcn_mfma_f32_16x16x32_bf16(a0, b[nf], acc[0][nf], 0,0,0);
            acc[1][nf] = __builtin_amdgcn_mfma_f32_16x16x32_bf16(a1, b[nf], acc[1][nf], 0,0,0);
        }
    }
    #pragma unroll
    for(int m=0;m<2;m++){
        #pragma unroll
        for(int r=0;r<4;r++){
            int row = row0 + m*16 + hi*4 + r;
            if(row < N){
                float dv = dinv ? dinv[row] : 1.0f;
                #pragma unroll
                for(int nf=0;nf<4;nf++)
                    Z[(size_t)row*HID + wc*64 + nf*16 + lr] = f2bf(acc[m][nf][r]*dv);
            }
        }
    }
}

// input block epilogue: o = LN(gelu(Z+b)); h0b=xb=bf16(o); xcur=o
__global__ __launch_bounds__(256) void k_ln_in(const ushort* __restrict__ Zb, const float* __restrict__ b,
    const float* __restrict__ g, const float* __restrict__ be,
    ushort* __restrict__ h0b, float* __restrict__ xcur, ushort* __restrict__ xb, int N)
{
    int wave = threadIdx.x>>6, lane = threadIdx.x&63;
    int n = blockIdx.x*4 + wave;
    if(n>=N) return;
    float4 v = bf4_to_f4(reinterpret_cast<const ushort4*>(Zb)[(size_t)n*64 + lane]);
    float4 bb = reinterpret_cast<const float4*>(b)[lane];
    v.x = gelu_tanh(v.x+bb.x);
    v.y = gelu_tanh(v.y+bb.y);
    v.z = gelu_tanh(v.z+bb.z);
    v.w = gelu_tanh(v.w+bb.w);
    float s1 = wave_sum(v.x+v.y+v.z+v.w);
    float mu = s1*(1.0f/256.0f);
    float dx=v.x-mu, dy=v.y-mu, dz=v.z-mu, dw=v.w-mu;
    float s2 = wave_sum(dx*dx+dy*dy+dz*dz+dw*dw);
    float rs = rsqrtf(s2*(1.0f/256.0f)+1e-5f);
    float4 gg = reinterpret_cast<const float4*>(g)[lane];
    float4 b2 = reinterpret_cast<const float4*>(be)[lane];
    float4 o;
    o.x = dx*rs*gg.x + b2.x;
    o.y = dy*rs*gg.y + b2.y;
    o.z = dz*rs*gg.z + b2.z;
    o.w = dw*rs*gg.w + b2.w;
    ushort4 ob; ob.x=f2bf(o.x); ob.y=f2bf(o.y); ob.z=f2bf(o.z); ob.w=f2bf(o.w);
    reinterpret_cast<ushort4*>(h0b)[(size_t)n*64+lane]=ob;
    reinterpret_cast<ushort4*>(xb )[(size_t)n*64+lane]=ob;
    reinterpret_cast<float4*>(xcur)[(size_t)n*64+lane]=o;
}

// fused: acc = z[n] + sum_nbr z[src]; v=dinv[n]*acc+bc; o=LN(gelu(v));
// xcur += 0.9*o + 0.1*h0; xb = bf16(xcur)
__global__ __launch_bounds__(256) void k_agg_ln(const ushort* __restrict__ Zb,
    const int* __restrict__ indptr, const int* __restrict__ csr,
    const float* __restrict__ dinv, const float* __restrict__ bc,
    const float* __restrict__ gc, const float* __restrict__ bec,
    const ushort* __restrict__ h0b, float* __restrict__ xcur,
    ushort* __restrict__ xb, int N)
{
    int wave = threadIdx.x>>6, lane = threadIdx.x&63;
    int n = blockIdx.x*4 + wave;
    if(n>=N) return;
    const ushort4* Z4 = reinterpret_cast<const ushort4*>(Zb);
    float4 acc = bf4_to_f4(Z4[(size_t)n*64+lane]);
    int e0 = indptr[n], e1 = indptr[n+1];
    for(int e=e0;e<e1;e++){
        int s = csr[e];
        float4 zv = bf4_to_f4(Z4[(size_t)s*64+lane]);
        acc.x+=zv.x; acc.y+=zv.y; acc.z+=zv.z; acc.w+=zv.w;
    }
    float dn = dinv[n];
    float4 bb = reinterpret_cast<const float4*>(bc)[lane];
    float4 v;
    v.x = gelu_tanh(fmaf(dn,acc.x,bb.x));
    v.y = gelu_tanh(fmaf(dn,acc.y,bb.y));
    v.z = gelu_tanh(fmaf(dn,acc.z,bb.z));
    v.w = gelu_tanh(fmaf(dn,acc.w,bb.w));
    float s1 = wave_sum(v.x+v.y+v.z+v.w);
    float mu = s1*(1.0f/256.0f);
    float dx=v.x-mu, dy=v.y-mu, dz=v.z-mu, dw=v.w-mu;
    float s2 = wave_sum(dx*dx+dy*dy+dz*dz+dw*dw);
    float rs = rsqrtf(s2*(1.0f/256.0f)+1e-5f);
    float4 gg = reinterpret_cast<const float4*>(gc)[lane];
    float4 b2 = reinterpret_cast<const float4*>(bec)[lane];
    float4 o;
    o.x = dx*rs*gg.x + b2.x;
    o.y = dy*rs*gg.y + b2.y;
    o.z = dz*rs*gg.z + b2.z;
    o.w = dw*rs*gg.w + b2.w;
    float4 h = bf4_to_f4(reinterpret_cast<const ushort4*>(h0b)[(size_t)n*64+lane]);
    float4 xc = reinterpret_cast<float4*>(xcur)[(size_t)n*64+lane];
    xc.x += 0.9f*o.x + 0.1f*h.x;
    xc.y += 0.9f*o.y + 0.1f*h.y;
    xc.z += 0.9f*o.z + 0.1f*h.z;
    xc.w += 0.9f*o.w + 0.1f*h.w;
    reinterpret_cast<float4*>(xcur)[(size_t)n*64+lane] = xc;
    ushort4 xbv; xbv.x=f2bf(xc.x); xbv.y=f2bf(xc.y); xbv.z=f2bf(xc.z); xbv.w=f2bf(xc.w);
    reinterpret_cast<ushort4*>(xb)[(size_t)n*64+lane] = xbv;
}

extern "C" void kernel_launch(void* const* d_in, const int* in_sizes, int n_in,
                              void* d_out, int out_size, void* d_ws, size_t ws_size,
                              hipStream_t stream){
    const float* x     = (const float*)d_in[0];
    const int*   ei    = (const int*)d_in[1];
    const float* W_in  = (const float*)d_in[2];
    const float* b_in  = (const float*)d_in[3];
    const float* g_in  = (const float*)d_in[4];
    const float* be_in = (const float*)d_in[5];
    const float* Wc    = (const float*)d_in[6];
    const float* bc    = (const float*)d_in[7];
    const float* gc    = (const float*)d_in[8];
    const float* bec   = (const float*)d_in[9];
    const int N = in_sizes[0]/128;
    const int E = in_sizes[1]/2;
    const int* src = ei;
    const int* dst = ei + E;
    float* xcur = (float*)d_out;

    char* w = (char*)d_ws;
    ushort* zb   = (ushort*)w; w += (size_t)N*HID*2;
    ushort* xb   = (ushort*)w; w += (size_t)N*HID*2;
    ushort* h0b  = (ushort*)w; w += (size_t)N*HID*2;
    ushort* xin  = (ushort*)w; w += (size_t)N*128*2;
    ushort* wbin = (ushort*)w; w += (size_t)128*256*2;
    ushort* wbc  = (ushort*)w; w += (size_t)6*65536*2;
    float* dinv  = (float*)w;  w += (size_t)N*4;
    int* cnt     = (int*)w;    w += (size_t)N*4;
    int* cursor  = (int*)w;    w += (size_t)N*4;
    int* csr     = (int*)w;    w += (size_t)E*4;
    int* indptr  = (int*)w;    w += (size_t)(N+1)*4;

    k_zero_cnt<<<(N+255)/256,256,0,stream>>>(cnt,N);
    k_count<<<(E+255)/256,256,0,stream>>>(dst,cnt,E);
    k_scan<<<1,1024,0,stream>>>(cnt,indptr,cursor,dinv,N);
    k_fill<<<(E+255)/256,256,0,stream>>>(src,dst,cursor,csr,E);

    k_cvt<<<((N*128/4)+255)/256,256,0,stream>>>(x, xin, N*128/4);
    k_cvt_win<<<(128*256+255)/256,256,0,stream>>>(W_in, wbin);
    k_cvt_wc<<<(6*65536+255)/256,256,0,stream>>>(Wc, wbc);

    k_gemm_mfma<128><<<(N+31)/32,256,0,stream>>>(xin, wbin, nullptr, zb, N);
    k_ln_in<<<(N+3)/4,256,0,stream>>>(zb, b_in, g_in, be_in, h0b, xcur, xb, N);
    for(int l=0;l<6;l++){
        k_gemm_mfma<256><<<(N+31)/32,256,0,stream>>>(xb, wbc+(size_t)l*65536, dinv, zb, N);
        k_agg_ln<<<(N+3)/4,256,0,stream>>>(zb, indptr, csr, dinv, bc+(size_t)l*HID,
                                           gc+(size_t)l*HID, bec+(size_t)l*HID, h0b, xcur, xb, N);
    }
}

// Round 3
// 361.736 us; speedup vs baseline: 2.5801x; 1.3957x over previous
//
#include <hip/hip_runtime.h>
#include <hip/hip_bf16.h>
#include <math.h>

#define HID 256
typedef __attribute__((ext_vector_type(8))) short s16x8;
typedef __attribute__((ext_vector_type(4))) float f32x4;

__device__ __forceinline__ ushort f2bf(float f){
    uint u = __float_as_uint(f);
    u += 0x7FFF + ((u>>16)&1);
    return (ushort)(u>>16);
}
__device__ __forceinline__ float bf2f(ushort b){
    return __uint_as_float(((uint)b)<<16);
}
__device__ __forceinline__ float4 bf4_to_f4(ushort4 u){
    return make_float4(bf2f(u.x), bf2f(u.y), bf2f(u.z), bf2f(u.w));
}

// gelu tanh-approx, tanh via fast exp: tanh(u) = 1 - 2/(1+exp(2u))
__device__ __forceinline__ float gelu_tanh(float x){
    float u = 0.7978845608028654f*(x + 0.044715f*x*x*x);
    float t = 1.0f - 2.0f/(1.0f + __expf(2.0f*u));
    return 0.5f*x*(1.0f+t);
}

__global__ void k_count(const int* __restrict__ dst, int* __restrict__ cnt, int E){
    int e = blockIdx.x*blockDim.x + threadIdx.x;
    if(e<E) atomicAdd(&cnt[dst[e]], 1);
}

// stage 1: per-block (1024 elems) scan; tsum = per-thread exclusive prefix, bsum = block total
__global__ __launch_bounds__(256) void k_scan1(const int* __restrict__ cnt,
    int* __restrict__ tsum, int* __restrict__ bsum, int N){
    __shared__ int sm[256];
    int t = threadIdx.x, b = blockIdx.x;
    int base = b*1024 + t*4;
    int c0=0,c1=0,c2=0,c3=0;
    if(base+3 < N){
        int4 c = *reinterpret_cast<const int4*>(&cnt[base]);
        c0=c.x; c1=c.y; c2=c.z; c3=c.w;
    }else{
        if(base  <N) c0=cnt[base];
        if(base+1<N) c1=cnt[base+1];
        if(base+2<N) c2=cnt[base+2];
        if(base+3<N) c3=cnt[base+3];
    }
    int s = c0+c1+c2+c3;
    sm[t]=s; __syncthreads();
    for(int off=1; off<256; off<<=1){
        int v = sm[t];
        int a = (t>=off)? sm[t-off] : 0;
        __syncthreads();
        sm[t] = v+a;
        __syncthreads();
    }
    tsum[b*256+t] = sm[t]-s;
    if(t==255) bsum[b] = sm[255];
}

// stage 2: serial scan of block sums (B ~ 20), writes indptr[N]=total
__global__ void k_scan2(const int* __restrict__ bsum, int* __restrict__ boff,
    int* __restrict__ indptr, int B, int N){
    if(threadIdx.x==0 && blockIdx.x==0){
        int run=0;
        for(int i=0;i<B;i++){ boff[i]=run; run+=bsum[i]; }
        indptr[N]=run;
    }
}

// stage 3: write indptr/cursor/dinv
__global__ __launch_bounds__(256) void k_scan3(const int* __restrict__ cnt,
    const int* __restrict__ tsum, const int* __restrict__ boff,
    int* __restrict__ indptr, int* __restrict__ cursor, float* __restrict__ dinv, int N){
    int t = threadIdx.x, b = blockIdx.x;
    int base = b*1024 + t*4;
    int run = boff[b] + tsum[b*256+t];
    #pragma unroll
    for(int i=0;i<4;i++){
        int idx = base+i;
        if(idx<N){
            int c = cnt[idx];
            indptr[idx]=run; cursor[idx]=run;
            dinv[idx] = rsqrtf((float)(c+1));
            run += c;
        }
    }
}

__global__ void k_fill(const int* __restrict__ src, const int* __restrict__ dst,
    int* __restrict__ cursor, int* __restrict__ csr, int E){
    int e = blockIdx.x*blockDim.x + threadIdx.x;
    if(e<E){
        int pos = atomicAdd(&cursor[dst[e]], 1);
        csr[pos] = src[e];
    }
}

__global__ void k_cvt(const float* __restrict__ in, ushort* __restrict__ out, int total4){
    int i = blockIdx.x*blockDim.x + threadIdx.x;
    if(i < total4){
        float4 v = reinterpret_cast<const float4*>(in)[i];
        ushort4 o; o.x=f2bf(v.x); o.y=f2bf(v.y); o.z=f2bf(v.z); o.w=f2bf(v.w);
        reinterpret_cast<ushort4*>(out)[i] = o;
    }
}

// W [K][256] fp32 -> fragment-shuffled bf16: Wb[((kb*256+n)*4+hi)*8+ii], k = kb*32+hi*8+ii
__global__ void k_cvt_win(const float* __restrict__ W, ushort* __restrict__ Wb){
    int i = blockIdx.x*blockDim.x + threadIdx.x;
    if(i >= 128*256) return;
    int k = i >> 8, n = i & 255;
    int kb = k>>5, hi=(k>>3)&3, ii=k&7;
    Wb[((kb*256+n)*4+hi)*8 + ii] = f2bf(W[i]);
}
__global__ void k_cvt_wc(const float* __restrict__ W, ushort* __restrict__ Wb){
    int i = blockIdx.x*blockDim.x + threadIdx.x;
    if(i >= 6*65536) return;
    int l = i >> 16;
    int k = (i>>8)&255, n = i&255;
    int kb = k>>5, hi=(k>>3)&3, ii=k&7;
    Wb[l*65536 + ((kb*256+n)*4+hi)*8 + ii] = f2bf(W[i]);
}

// pure gather: yb[n] = bf16( dinv[n] * (xsc[n] + sum_{e in CSR[n]} xsc[src_e]) )
__global__ __launch_bounds__(256) void k_agg(const ushort* __restrict__ xsc,
    const int* __restrict__ indptr, const int* __restrict__ csr,
    const float* __restrict__ dinv, ushort* __restrict__ yb, int N)
{
    int wave = threadIdx.x>>6, lane = threadIdx.x&63;
    int n = blockIdx.x*4 + wave;
    if(n>=N) return;
    const ushort4* X4 = reinterpret_cast<const ushort4*>(xsc);
    float4 acc = bf4_to_f4(X4[(size_t)n*64+lane]);
    int e0 = indptr[n], e1 = indptr[n+1];
    int e = e0;
    for(; e+4<=e1; e+=4){
        int i0=csr[e], i1=csr[e+1], i2=csr[e+2], i3=csr[e+3];
        float4 v0 = bf4_to_f4(X4[(size_t)i0*64+lane]);
        float4 v1 = bf4_to_f4(X4[(size_t)i1*64+lane]);
        float4 v2 = bf4_to_f4(X4[(size_t)i2*64+lane]);
        float4 v3 = bf4_to_f4(X4[(size_t)i3*64+lane]);
        acc.x += (v0.x+v1.x)+(v2.x+v3.x);
        acc.y += (v0.y+v1.y)+(v2.y+v3.y);
        acc.z += (v0.z+v1.z)+(v2.z+v3.z);
        acc.w += (v0.w+v1.w)+(v2.w+v3.w);
    }
    for(; e<e1; e++){
        float4 v = bf4_to_f4(X4[(size_t)csr[e]*64+lane]);
        acc.x+=v.x; acc.y+=v.y; acc.z+=v.z; acc.w+=v.w;
    }
    float dn = dinv[n];
    ushort4 o; o.x=f2bf(dn*acc.x); o.y=f2bf(dn*acc.y); o.z=f2bf(dn*acc.z); o.w=f2bf(dn*acc.w);
    reinterpret_cast<ushort4*>(yb)[(size_t)n*64+lane] = o;
}

// Fused GEMM + bias + GELU + LN (+ blend for conv layers).
// G = A(bf16 NxK) * Wb(frag-shuffled) ; t = gelu(G + bp) ; o = LN(t)*gp + bep
// INPUT:  h0b = xsc0 = bf16(o) [xsc scaled by dinv], xcur = o
// CONV:   xcur += 0.9*o + 0.1*h0 ; xsc = bf16(dinv*xcur)
template<int K, bool INPUT>
__global__ __launch_bounds__(256) void k_gemm_fused(const ushort* __restrict__ A,
    const ushort* __restrict__ Wb,
    const float* __restrict__ bp, const float* __restrict__ gp, const float* __restrict__ bep,
    const float* __restrict__ dinv, ushort* __restrict__ h0b,
    float* __restrict__ xcur, ushort* __restrict__ xsc, int N)
{
    constexpr int KB = K/32;
    const int lane = threadIdx.x & 63;
    const int wc = threadIdx.x >> 6;
    const int lr = lane & 15;
    const int hi = lane >> 4;
    const int row0 = blockIdx.x*32;

    f32x4 acc[2][4];
    #pragma unroll
    for(int m=0;m<2;m++)
        #pragma unroll
        for(int n=0;n<4;n++){ acc[m][n].x=0.f; acc[m][n].y=0.f; acc[m][n].z=0.f; acc[m][n].w=0.f; }

    int r0 = row0 + lr;      if(r0 >= N) r0 = N-1;
    int r1 = row0 + 16 + lr; if(r1 >= N) r1 = N-1;
    const ushort* ap0 = A + (size_t)r0*K + hi*8;
    const ushort* ap1 = A + (size_t)r1*K + hi*8;
    const ushort* bpp = Wb + (wc*64 + lr)*32 + hi*8;

    s16x8 a0[2], a1[2], bb[2][4];
    a0[0] = *reinterpret_cast<const s16x8*>(ap0);
    a1[0] = *reinterpret_cast<const s16x8*>(ap1);
    #pragma unroll
    for(int nf=0;nf<4;nf++) bb[0][nf] = *reinterpret_cast<const s16x8*>(bpp + nf*512);

    #pragma unroll
    for(int kb=0; kb<KB; kb++){
        const int cur = kb&1, nxt = cur^1;
        if(kb+1 < KB){
            a0[nxt] = *reinterpret_cast<const s16x8*>(ap0 + (kb+1)*32);
            a1[nxt] = *reinterpret_cast<const s16x8*>(ap1 + (kb+1)*32);
            #pragma unroll
            for(int nf=0;nf<4;nf++)
                bb[nxt][nf] = *reinterpret_cast<const s16x8*>(bpp + (kb+1)*8192 + nf*512);
        }
        #pragma unroll
        for(int nf=0;nf<4;nf++){
            acc[0][nf] = __builtin_amdgcn_mfma_f32_16x16x32_bf16(a0[cur], bb[cur][nf], acc[0][nf], 0,0,0);
            acc[1][nf] = __builtin_amdgcn_mfma_f32_16x16x32_bf16(a1[cur], bb[cur][nf], acc[1][nf], 0,0,0);
        }
    }

    // ---- fused epilogue ----
    float bcv[4], gcv[4], bev[4];
    #pragma unroll
    for(int nf=0;nf<4;nf++){
        int col = wc*64 + nf*16 + lr;
        bcv[nf]=bp[col]; gcv[nf]=gp[col]; bev[nf]=bep[col];
    }
    __shared__ float sm1[32][4];
    __shared__ float sm2[32][4];
    // pass 1: gelu + partial sums per row
    #pragma unroll
    for(int m=0;m<2;m++){
        #pragma unroll
        for(int r=0;r<4;r++){
            float ls1=0.f, ls2=0.f;
            #pragma unroll
            for(int nf=0;nf<4;nf++){
                float t = gelu_tanh(acc[m][nf][r] + bcv[nf]);
                acc[m][nf][r] = t;
                ls1 += t; ls2 += t*t;
            }
            #pragma unroll
            for(int off=1; off<16; off<<=1){
                ls1 += __shfl_xor(ls1, off, 64);
                ls2 += __shfl_xor(ls2, off, 64);
            }
            if(lr==0){
                int row = m*16 + hi*4 + r;
                sm1[row][wc]=ls1; sm2[row][wc]=ls2;
            }
        }
    }
    __syncthreads();
    // pass 2: LN + blend + stores
    #pragma unroll
    for(int m=0;m<2;m++){
        #pragma unroll
        for(int r=0;r<4;r++){
            int row = m*16 + hi*4 + r;
            int grow = row0 + row;
            if(grow >= N) continue;
            float S1 = sm1[row][0]+sm1[row][1]+sm1[row][2]+sm1[row][3];
            float S2 = sm2[row][0]+sm2[row][1]+sm2[row][2]+sm2[row][3];
            float mu = S1*(1.0f/256.0f);
            float var = fmaxf(S2*(1.0f/256.0f) - mu*mu, 0.0f);
            float rs = rsqrtf(var + 1e-5f);
            float dv = dinv[grow];
            #pragma unroll
            for(int nf=0;nf<4;nf++){
                int col = wc*64 + nf*16 + lr;
                size_t idx = (size_t)grow*HID + col;
                float o = (acc[m][nf][r]-mu)*rs*gcv[nf] + bev[nf];
                if(INPUT){
                    h0b[idx] = f2bf(o);
                    xcur[idx] = o;
                    xsc[idx] = f2bf(dv*o);
                }else{
                    float h = bf2f(h0b[idx]);
                    float xc = xcur[idx] + 0.9f*o + 0.1f*h;
                    xcur[idx] = xc;
                    xsc[idx] = f2bf(dv*xc);
                }
            }
        }
    }
}

extern "C" void kernel_launch(void* const* d_in, const int* in_sizes, int n_in,
                              void* d_out, int out_size, void* d_ws, size_t ws_size,
                              hipStream_t stream){
    const float* x     = (const float*)d_in[0];
    const int*   ei    = (const int*)d_in[1];
    const float* W_in  = (const float*)d_in[2];
    const float* b_in  = (const float*)d_in[3];
    const float* g_in  = (const float*)d_in[4];
    const float* be_in = (const float*)d_in[5];
    const float* Wc    = (const float*)d_in[6];
    const float* bc    = (const float*)d_in[7];
    const float* gc    = (const float*)d_in[8];
    const float* bec   = (const float*)d_in[9];
    const int N = in_sizes[0]/128;
    const int E = in_sizes[1]/2;
    const int* src = ei;
    const int* dst = ei + E;
    float* xcur = (float*)d_out;
    const int B = (N+1023)/1024;

    char* w = (char*)d_ws;
    ushort* xsc  = (ushort*)w; w += (size_t)N*HID*2;
    ushort* yb   = (ushort*)w; w += (size_t)N*HID*2;
    ushort* h0b  = (ushort*)w; w += (size_t)N*HID*2;
    ushort* xin  = (ushort*)w; w += (size_t)N*128*2;
    ushort* wbin = (ushort*)w; w += (size_t)128*256*2;
    ushort* wbc  = (ushort*)w; w += (size_t)6*65536*2;
    float* dinv  = (float*)w;  w += (size_t)N*4;
    int* cnt     = (int*)w;    w += (size_t)N*4;
    int* cursor  = (int*)w;    w += (size_t)N*4;
    int* csr     = (int*)w;    w += (size_t)E*4;
    int* indptr  = (int*)w;    w += (size_t)(N+1)*4;
    int* tsum    = (int*)w;    w += (size_t)B*256*4;
    int* bsum    = (int*)w;    w += (size_t)B*4;
    int* boff    = (int*)w;    w += (size_t)B*4;

    hipMemsetAsync(cnt, 0, (size_t)N*4, stream);
    k_count<<<(E+255)/256,256,0,stream>>>(dst,cnt,E);
    k_scan1<<<B,256,0,stream>>>(cnt, tsum, bsum, N);
    k_scan2<<<1,64,0,stream>>>(bsum, boff, indptr, B, N);
    k_scan3<<<B,256,0,stream>>>(cnt, tsum, boff, indptr, cursor, dinv, N);
    k_fill<<<(E+255)/256,256,0,stream>>>(src,dst,cursor,csr,E);

    k_cvt<<<((N*128/4)+255)/256,256,0,stream>>>(x, xin, N*128/4);
    k_cvt_win<<<(128*256+255)/256,256,0,stream>>>(W_in, wbin);
    k_cvt_wc<<<(6*65536+255)/256,256,0,stream>>>(Wc, wbc);

    const int GB = (N+31)/32;
    k_gemm_fused<128,true><<<GB,256,0,stream>>>(xin, wbin, b_in, g_in, be_in,
                                                dinv, h0b, xcur, xsc, N);
    for(int l=0;l<6;l++){
        k_agg<<<(N+3)/4,256,0,stream>>>(xsc, indptr, csr, dinv, yb, N);
        k_gemm_fused<256,false><<<GB,256,0,stream>>>(yb, wbc+(size_t)l*65536,
            bc+(size_t)l*HID, gc+(size_t)l*HID, bec+(size_t)l*HID,
            dinv, h0b, xcur, xsc, N);
    }
}